// Round 2
// baseline (973.083 us; speedup 1.0000x reference)
//
#include <hip/hip_runtime.h>
#include <hip/hip_bf16.h>
#include <math.h>

#define NND 50000
#define NE  1200000
#define INCH 128
#define HID 64
#define H2  32
#define NL  3
#define BSZ 10000
#define EPS_RES 0.1f
#define BN_EPS 1e-5f

// ---------------- degree / CSR build ----------------

__global__ __launch_bounds__(256) void deg_init_kernel(int* __restrict__ deg, int n) {
    int i = blockIdx.x * 256 + threadIdx.x;
    if (i < n) deg[i] = 1;  // self-loop
}

__global__ __launch_bounds__(256) void deg_count_kernel(const int* __restrict__ dst, int* __restrict__ deg, int ne) {
    int e = blockIdx.x * 256 + threadIdx.x;
    if (e < ne) atomicAdd(&deg[dst[e]], 1);
}

__global__ __launch_bounds__(256) void dinv_kernel(const int* __restrict__ deg, float* __restrict__ dinv, int n) {
    int i = blockIdx.x * 256 + threadIdx.x;
    if (i < n) dinv[i] = rsqrtf((float)deg[i]);
}

// inclusive scan of 1024-element chunks
__global__ __launch_bounds__(1024) void scanA_kernel(const int* __restrict__ deg, int* __restrict__ incl,
                                                     int* __restrict__ bsum, int n) {
    __shared__ int ls[1024];
    int tid = threadIdx.x;
    int i = blockIdx.x * 1024 + tid;
    int d = (i < n) ? deg[i] : 0;
    ls[tid] = d;
    __syncthreads();
    for (int off = 1; off < 1024; off <<= 1) {
        int t = (tid >= off) ? ls[tid - off] : 0;
        __syncthreads();
        ls[tid] += t;
        __syncthreads();
    }
    if (i < n) incl[i] = ls[tid];
    if (tid == 1023) bsum[blockIdx.x] = ls[1023];
}

__global__ void scanB_kernel(const int* __restrict__ bsum, int* __restrict__ boff,
                             int* __restrict__ offsets, int nblk, int n) {
    if (threadIdx.x == 0 && blockIdx.x == 0) {
        int run = 0;
        for (int j = 0; j < nblk; j++) { boff[j] = run; run += bsum[j]; }
        offsets[n] = run;
    }
}

__global__ __launch_bounds__(256) void scanC_kernel(const int* __restrict__ incl, const int* __restrict__ deg,
                                                    const int* __restrict__ boff, int* __restrict__ offsets,
                                                    int* __restrict__ csr, int* __restrict__ cursor, int n) {
    int i = blockIdx.x * 256 + threadIdx.x;
    if (i >= n) return;
    int e = incl[i] - deg[i] + boff[i >> 10];  // exclusive
    offsets[i] = e;
    csr[e] = i;          // self-loop first
    cursor[i] = e + 1;
}

__global__ __launch_bounds__(256) void scatter_kernel(const int* __restrict__ src, const int* __restrict__ dst,
                                                      int* __restrict__ cursor, int* __restrict__ csr, int ne) {
    int e = blockIdx.x * 256 + threadIdx.x;
    if (e >= ne) return;
    int v = dst[e];
    int pos = atomicAdd(&cursor[v], 1);
    csr[pos] = src[e];
}

// ---------------- input projection: x0 = relu(x @ W_in + b_in) ----------------
// 16 rows per block, 256 threads, each thread 4 outputs
__global__ __launch_bounds__(256) void gemm_in_kernel(const float* __restrict__ x, const float* __restrict__ W,
                                                      const float* __restrict__ b, float* __restrict__ x0) {
    __shared__ float Wl[INCH * HID];   // 32 KB
    __shared__ float xs[16 * INCH];    // 8 KB
    int t = threadIdx.x;
    for (int i = t; i < INCH * HID; i += 256) Wl[i] = W[i];
    size_t rowbase = (size_t)blockIdx.x * 16;
    for (int i = t; i < 16 * INCH; i += 256) xs[i] = x[rowbase * INCH + i];
    __syncthreads();
    int col = t & 63, rg = t >> 6;
    float a0 = 0.f, a1 = 0.f, a2 = 0.f, a3 = 0.f;
    for (int k = 0; k < INCH; k++) {
        float wk = Wl[k * HID + col];
        a0 = fmaf(xs[(rg * 4 + 0) * INCH + k], wk, a0);
        a1 = fmaf(xs[(rg * 4 + 1) * INCH + k], wk, a1);
        a2 = fmaf(xs[(rg * 4 + 2) * INCH + k], wk, a2);
        a3 = fmaf(xs[(rg * 4 + 3) * INCH + k], wk, a3);
    }
    float bb = b[col];
    size_t r = rowbase + rg * 4;
    x0[(r + 0) * HID + col] = fmaxf(a0 + bb, 0.f);
    x0[(r + 1) * HID + col] = fmaxf(a1 + bb, 0.f);
    x0[(r + 2) * HID + col] = fmaxf(a2 + bb, 0.f);
    x0[(r + 3) * HID + col] = fmaxf(a3 + bb, 0.f);
}

// ---------------- attention projections ----------------
__global__ __launch_bounds__(256) void attn_kernel(const float* __restrict__ h, const float* __restrict__ attl,
                                                   const float* __restrict__ attr, float* __restrict__ al,
                                                   float* __restrict__ ar, int n) {
    int w = (blockIdx.x * 256 + threadIdx.x) >> 6;
    int lane = threadIdx.x & 63;
    if (w >= n) return;
    float hv = h[(size_t)w * HID + lane];
    float pl = hv * attl[lane];
    float pr = hv * attr[lane];
    for (int off = 32; off > 0; off >>= 1) {
        pl += __shfl_xor(pl, off);
        pr += __shfl_xor(pr, off);
    }
    if (lane == 0) { al[w] = pl; ar[w] = pr; }
}

// ---------------- aggregate: y[v] = relu(sum_in h[u]*coef + eps*x0[v]) ----------------
__global__ __launch_bounds__(256) void aggregate_kernel(const float* __restrict__ h, const float* __restrict__ x0,
                                                        const float* __restrict__ al, const float* __restrict__ ar,
                                                        const float* __restrict__ dinv,
                                                        const int* __restrict__ offsets, const int* __restrict__ csr,
                                                        float* __restrict__ y, int n) {
    int v = (blockIdx.x * 256 + threadIdx.x) >> 6;
    int lane = threadIdx.x & 63;
    if (v >= n) return;
    int beg = offsets[v], end = offsets[v + 1];
    float arv = ar[v], dv = dinv[v];
    float acc = 0.f;
    for (int p = beg; p < end; ++p) {
        int u = csr[p];
        float coef = tanhf(al[u] + arv) * (dinv[u] * dv);
        acc = fmaf(h[(size_t)u * HID + lane], coef, acc);
    }
    float val = fmaf(EPS_RES, x0[(size_t)v * HID + lane], acc);
    y[(size_t)v * HID + lane] = fmaxf(val, 0.f);
}

// ---------------- batchnorm ----------------
template <int C>
__global__ __launch_bounds__(256) void bn_stats_kernel(const float* __restrict__ y, int rows,
                                                       float* __restrict__ sum, float* __restrict__ sumsq) {
    const int RPB = 256 / C;
    int c = threadIdx.x & (C - 1);
    int r0 = blockIdx.x * RPB + threadIdx.x / C;
    int stride = gridDim.x * RPB;
    float s = 0.f, q = 0.f;
    for (int r = r0; r < rows; r += stride) {
        float v = y[(size_t)r * C + c];
        s += v;
        q = fmaf(v, v, q);
    }
    __shared__ float ls[256], lq[256];
    ls[threadIdx.x] = s; lq[threadIdx.x] = q;
    __syncthreads();
    if (threadIdx.x < C) {
        float ts = 0.f, tq = 0.f;
        for (int j = 0; j < RPB; j++) { ts += ls[c + j * C]; tq += lq[c + j * C]; }
        atomicAdd(&sum[c], ts);
        atomicAdd(&sumsq[c], tq);
    }
}

__global__ void bn_finalize_kernel(const float* __restrict__ sum, const float* __restrict__ sumsq,
                                   const float* __restrict__ g, const float* __restrict__ b,
                                   float rows_inv, int C, float* __restrict__ scale, float* __restrict__ shift) {
    int c = threadIdx.x;
    if (c >= C) return;
    float mean = sum[c] * rows_inv;
    float var = sumsq[c] * rows_inv - mean * mean;
    float sc = g[c] * rsqrtf(var + BN_EPS);
    scale[c] = sc;
    shift[c] = b[c] - mean * sc;
}

__global__ __launch_bounds__(256) void bn_apply_kernel(float* __restrict__ y, const float* __restrict__ scale,
                                                       const float* __restrict__ shift, int n4) {
    int i = blockIdx.x * 256 + threadIdx.x;
    if (i >= n4) return;
    float4 v = ((float4*)y)[i];
    int cb = (i * 4) & 63;
    v.x = fmaf(v.x, scale[cb + 0], shift[cb + 0]);
    v.y = fmaf(v.y, scale[cb + 1], shift[cb + 1]);
    v.z = fmaf(v.z, scale[cb + 2], shift[cb + 2]);
    v.w = fmaf(v.w, scale[cb + 3], shift[cb + 3]);
    ((float4*)y)[i] = v;
}

// ---------------- MLP head ----------------
// z1 = h[:B] @ W1 + b1   (B x 64 x 64)
__global__ __launch_bounds__(256) void mlp1_kernel(const float* __restrict__ h, const float* __restrict__ W,
                                                   const float* __restrict__ b, float* __restrict__ z1) {
    __shared__ float Wl[HID * HID];  // 16 KB
    __shared__ float xs[16 * HID];   // 4 KB
    int t = threadIdx.x;
    for (int i = t; i < HID * HID; i += 256) Wl[i] = W[i];
    size_t rowbase = (size_t)blockIdx.x * 16;
    for (int i = t; i < 16 * HID; i += 256) xs[i] = h[rowbase * HID + i];
    __syncthreads();
    int col = t & 63, rg = t >> 6;
    float a0 = 0.f, a1 = 0.f, a2 = 0.f, a3 = 0.f;
    for (int k = 0; k < HID; k++) {
        float wk = Wl[k * HID + col];
        a0 = fmaf(xs[(rg * 4 + 0) * HID + k], wk, a0);
        a1 = fmaf(xs[(rg * 4 + 1) * HID + k], wk, a1);
        a2 = fmaf(xs[(rg * 4 + 2) * HID + k], wk, a2);
        a3 = fmaf(xs[(rg * 4 + 3) * HID + k], wk, a3);
    }
    float bb = b[col];
    size_t r = rowbase + rg * 4;
    z1[(r + 0) * HID + col] = a0 + bb;
    z1[(r + 1) * HID + col] = a1 + bb;
    z1[(r + 2) * HID + col] = a2 + bb;
    z1[(r + 3) * HID + col] = a3 + bb;
}

// z2 = relu(bn1(z1)) @ W2 + b2   (B x 64 x 32)
__global__ __launch_bounds__(256) void mlp2_kernel(const float* __restrict__ z1, const float* __restrict__ scale,
                                                   const float* __restrict__ shift, const float* __restrict__ W,
                                                   const float* __restrict__ b, float* __restrict__ z2) {
    __shared__ float Wl[HID * H2];   // 8 KB
    __shared__ float as[16 * HID];   // 4 KB
    int t = threadIdx.x;
    for (int i = t; i < HID * H2; i += 256) Wl[i] = W[i];
    size_t rowbase = (size_t)blockIdx.x * 16;
    for (int i = t; i < 16 * HID; i += 256) {
        int c = i & 63;
        float v = z1[rowbase * HID + i];
        as[i] = fmaxf(fmaf(v, scale[c], shift[c]), 0.f);
    }
    __syncthreads();
    int col = t & 31, rg = t >> 5;  // 8 groups x 2 rows
    float a0 = 0.f, a1 = 0.f;
    for (int k = 0; k < HID; k++) {
        float wk = Wl[k * H2 + col];
        a0 = fmaf(as[(rg * 2 + 0) * HID + k], wk, a0);
        a1 = fmaf(as[(rg * 2 + 1) * HID + k], wk, a1);
    }
    float bb = b[col];
    size_t r = rowbase + rg * 2;
    z2[(r + 0) * H2 + col] = a0 + bb;
    z2[(r + 1) * H2 + col] = a1 + bb;
}

// out = relu(bn2(z2)) @ W3 + b3
__global__ __launch_bounds__(256) void mlp3_kernel(const float* __restrict__ z2, const float* __restrict__ scale,
                                                   const float* __restrict__ shift, const float* __restrict__ W3,
                                                   const float* __restrict__ b3, float* __restrict__ out, int rows) {
    int i = blockIdx.x * 256 + threadIdx.x;
    if (i >= rows) return;
    float acc = 0.f;
#pragma unroll
    for (int k = 0; k < H2; k++) {
        float v = fmaxf(fmaf(z2[(size_t)i * H2 + k], scale[k], shift[k]), 0.f);
        acc = fmaf(v, W3[k], acc);
    }
    out[i] = acc + b3[0];
}

// ---------------- launch ----------------
extern "C" void kernel_launch(void* const* d_in, const int* in_sizes, int n_in,
                              void* d_out, int out_size, void* d_ws, size_t ws_size,
                              hipStream_t stream) {
    const float* x     = (const float*)d_in[0];
    const int*   ei    = (const int*)d_in[1];
    const int*   src   = ei;
    const int*   dst   = ei + NE;
    const float* W_in  = (const float*)d_in[3];
    const float* b_in  = (const float*)d_in[4];
    const float* att_l = (const float*)d_in[5];
    const float* att_r = (const float*)d_in[6];
    const float* bn_g  = (const float*)d_in[7];
    const float* bn_b  = (const float*)d_in[8];
    const float* W1    = (const float*)d_in[9];
    const float* b1    = (const float*)d_in[10];
    const float* g1    = (const float*)d_in[11];
    const float* be1   = (const float*)d_in[12];
    const float* W2    = (const float*)d_in[13];
    const float* b2    = (const float*)d_in[14];
    const float* g2    = (const float*)d_in[15];
    const float* be2   = (const float*)d_in[16];
    const float* W3    = (const float*)d_in[17];
    const float* b3    = (const float*)d_in[18];
    float* out = (float*)d_out;

    char* p = (char*)d_ws;
    auto carve = [&](size_t bytes) -> void* {
        void* r = (void*)p;
        p += (bytes + 255) & ~(size_t)255;
        return r;
    };
    int*   deg     = (int*)carve((size_t)NND * 4);
    int*   cursor  = (int*)carve((size_t)NND * 4);
    int*   incl    = (int*)carve((size_t)NND * 4);
    int*   offsets = (int*)carve((size_t)(NND + 1) * 4);
    int*   bsum    = (int*)carve(64 * 4);
    int*   boff    = (int*)carve(64 * 4);
    int*   csr     = (int*)carve((size_t)(NE + NND) * 4);
    float* dinv    = (float*)carve((size_t)NND * 4);
    float* al      = (float*)carve((size_t)NND * 4);
    float* ar      = (float*)carve((size_t)NND * 4);
    float* x0      = (float*)carve((size_t)NND * HID * 4);
    float* hA      = (float*)carve((size_t)NND * HID * 4);
    float* hB      = (float*)carve((size_t)NND * HID * 4);
    float* bn_sum  = (float*)carve(128 * 4);  // sum[64] + sumsq[64] contiguous
    float* bn_sq   = bn_sum + 64;
    float* scale   = (float*)carve(64 * 4);
    float* shift   = (float*)carve(64 * 4);
    float* z1      = (float*)carve((size_t)BSZ * HID * 4);
    float* z2      = (float*)carve((size_t)BSZ * H2 * 4);

    const int nblkN = (NND + 255) / 256;       // 196
    const int nblkE = (NE + 255) / 256;        // 4688
    const int nscan = (NND + 1023) / 1024;     // 49

    // --- CSR build ---
    deg_init_kernel<<<nblkN, 256, 0, stream>>>(deg, NND);
    deg_count_kernel<<<nblkE, 256, 0, stream>>>(dst, deg, NE);
    dinv_kernel<<<nblkN, 256, 0, stream>>>(deg, dinv, NND);
    scanA_kernel<<<nscan, 1024, 0, stream>>>(deg, incl, bsum, NND);
    scanB_kernel<<<1, 64, 0, stream>>>(bsum, boff, offsets, nscan, NND);
    scanC_kernel<<<nblkN, 256, 0, stream>>>(incl, deg, boff, offsets, csr, cursor, NND);
    scatter_kernel<<<nblkE, 256, 0, stream>>>(src, dst, cursor, csr, NE);

    // --- input projection ---
    gemm_in_kernel<<<NND / 16, 256, 0, stream>>>(x, W_in, b_in, x0);

    // --- 3 layers: ping-pong hA/hB, never read+write same buffer ---
    const float* h_in = x0;
    float* bufs[2] = {hA, hB};
    for (int l = 0; l < NL; l++) {
        float* y = bufs[l & 1];   // l0: hA (reads x0), l1: hB (reads hA), l2: hA (reads hB)
        attn_kernel<<<NND / 4, 256, 0, stream>>>(h_in, att_l + l * HID, att_r + l * HID, al, ar, NND);
        aggregate_kernel<<<NND / 4, 256, 0, stream>>>(h_in, x0, al, ar, dinv, offsets, csr, y, NND);
        hipMemsetAsync(bn_sum, 0, 128 * sizeof(float), stream);
        bn_stats_kernel<64><<<64, 256, 0, stream>>>(y, NND, bn_sum, bn_sq);
        bn_finalize_kernel<<<1, 64, 0, stream>>>(bn_sum, bn_sq, bn_g + l * HID, bn_b + l * HID,
                                                 1.0f / NND, HID, scale, shift);
        bn_apply_kernel<<<(NND * HID / 4 + 255) / 256, 256, 0, stream>>>(y, scale, shift, NND * HID / 4);
        h_in = y;
    }
    // after loop: h_in == hA (final h)

    // --- MLP head on first BSZ rows ---
    mlp1_kernel<<<BSZ / 16, 256, 0, stream>>>(h_in, W1, b1, z1);
    hipMemsetAsync(bn_sum, 0, 128 * sizeof(float), stream);
    bn_stats_kernel<64><<<64, 256, 0, stream>>>(z1, BSZ, bn_sum, bn_sq);
    bn_finalize_kernel<<<1, 64, 0, stream>>>(bn_sum, bn_sq, g1, be1, 1.0f / BSZ, HID, scale, shift);

    mlp2_kernel<<<BSZ / 16, 256, 0, stream>>>(z1, scale, shift, W2, b2, z2);
    hipMemsetAsync(bn_sum, 0, 128 * sizeof(float), stream);
    bn_stats_kernel<32><<<64, 256, 0, stream>>>(z2, BSZ, bn_sum, bn_sq);
    bn_finalize_kernel<<<1, 64, 0, stream>>>(bn_sum, bn_sq, g2, be2, 1.0f / BSZ, H2, scale, shift);

    mlp3_kernel<<<(BSZ + 255) / 256, 256, 0, stream>>>(z2, scale, shift, W3, b3, out, BSZ);
}

// Round 3
// 733.477 us; speedup vs baseline: 1.3267x; 1.3267x over previous
//
#include <hip/hip_runtime.h>
#include <hip/hip_bf16.h>
#include <math.h>

#define NND 50000
#define NE  1200000
#define TOT (NE + NND)
#define INCH 128
#define HID 64
#define H2  32
#define NL  3
#define BSZ 10000
#define EPS_RES 0.1f
#define BN_EPS 1e-5f

// ---------------- degree / CSR build ----------------

__global__ __launch_bounds__(256) void deg_count_kernel(const int* __restrict__ dst, int* __restrict__ deg, int ne) {
    int e = blockIdx.x * 256 + threadIdx.x;
    if (e < ne) atomicAdd(&deg[dst[e]], 1);
}

// inclusive scan of 1024-element chunks over (deg+1); also emits dinv
__global__ __launch_bounds__(1024) void scanA_kernel(const int* __restrict__ deg, int* __restrict__ incl,
                                                     int* __restrict__ bsum, float* __restrict__ dinv, int n) {
    __shared__ int ls[1024];
    int tid = threadIdx.x;
    int i = blockIdx.x * 1024 + tid;
    int d = (i < n) ? (deg[i] + 1) : 0;   // +1 = self-loop
    if (i < n) dinv[i] = rsqrtf((float)d);
    ls[tid] = d;
    __syncthreads();
    for (int off = 1; off < 1024; off <<= 1) {
        int t = (tid >= off) ? ls[tid - off] : 0;
        __syncthreads();
        ls[tid] += t;
        __syncthreads();
    }
    if (i < n) incl[i] = ls[tid];
    if (tid == 1023) bsum[blockIdx.x] = ls[1023];
}

// wave-level scan over per-chunk sums (nblk <= 64)
__global__ void scanB_kernel(const int* __restrict__ bsum, int* __restrict__ boff,
                             int* __restrict__ offsets, int nblk, int n) {
    int lane = threadIdx.x;
    int mine = (lane < nblk) ? bsum[lane] : 0;
    int v = mine;
    for (int off = 1; off < 64; off <<= 1) {
        int t = __shfl_up(v, off);
        if (lane >= off) v += t;
    }
    if (lane < nblk) boff[lane] = v - mine;
    if (lane == 63) offsets[n] = v;
}

__global__ __launch_bounds__(256) void scanC_kernel(const int* __restrict__ incl, const int* __restrict__ deg,
                                                    const int* __restrict__ boff, const float* __restrict__ dinv,
                                                    int* __restrict__ offsets, int* __restrict__ csr,
                                                    int* __restrict__ rowid, float* __restrict__ norm,
                                                    int* __restrict__ cursor, int n) {
    int i = blockIdx.x * 256 + threadIdx.x;
    if (i >= n) return;
    int e = incl[i] - (deg[i] + 1) + boff[i >> 10];  // exclusive offset
    offsets[i] = e;
    csr[e] = i;          // self-loop first
    rowid[e] = i;
    float dv = dinv[i];
    norm[e] = dv * dv;
    cursor[i] = e + 1;
}

__global__ __launch_bounds__(256) void scatter_kernel(const int* __restrict__ src, const int* __restrict__ dst,
                                                      const float* __restrict__ dinv,
                                                      int* __restrict__ cursor, int* __restrict__ csr,
                                                      int* __restrict__ rowid, float* __restrict__ norm, int ne) {
    int e = blockIdx.x * 256 + threadIdx.x;
    if (e >= ne) return;
    int u = src[e], v = dst[e];
    int pos = atomicAdd(&cursor[v], 1);
    csr[pos] = u;
    rowid[pos] = v;
    norm[pos] = dinv[u] * dinv[v];
}

// ---------------- input projection: x0 = relu(x @ W_in + b_in), fused attn layer 0 ----------------
__global__ __launch_bounds__(256) void gemm_in_kernel(const float* __restrict__ x, const float* __restrict__ W,
                                                      const float* __restrict__ b,
                                                      const float* __restrict__ attl, const float* __restrict__ attr,
                                                      float* __restrict__ x0,
                                                      float* __restrict__ al, float* __restrict__ ar) {
    __shared__ float Wl[INCH * HID];   // 32 KB
    __shared__ float xs[16 * INCH];    // 8 KB
    int t = threadIdx.x;
    for (int i = t; i < INCH * HID; i += 256) Wl[i] = W[i];
    size_t rowbase = (size_t)blockIdx.x * 16;
    for (int i = t; i < 16 * INCH; i += 256) xs[i] = x[rowbase * INCH + i];
    __syncthreads();
    int col = t & 63, rg = t >> 6;
    float a0 = 0.f, a1 = 0.f, a2 = 0.f, a3 = 0.f;
    for (int k = 0; k < INCH; k++) {
        float wk = Wl[k * HID + col];
        a0 = fmaf(xs[(rg * 4 + 0) * INCH + k], wk, a0);
        a1 = fmaf(xs[(rg * 4 + 1) * INCH + k], wk, a1);
        a2 = fmaf(xs[(rg * 4 + 2) * INCH + k], wk, a2);
        a3 = fmaf(xs[(rg * 4 + 3) * INCH + k], wk, a3);
    }
    float bb = b[col];
    a0 = fmaxf(a0 + bb, 0.f); a1 = fmaxf(a1 + bb, 0.f);
    a2 = fmaxf(a2 + bb, 0.f); a3 = fmaxf(a3 + bb, 0.f);
    size_t r = rowbase + rg * 4;
    x0[(r + 0) * HID + col] = a0;
    x0[(r + 1) * HID + col] = a1;
    x0[(r + 2) * HID + col] = a2;
    x0[(r + 3) * HID + col] = a3;
    // fused attention dots for layer 0 (wave rg holds rows r..r+3, lane=channel)
    float wl = attl[col], wr = attr[col];
    float p0 = a0 * wl, q0 = a0 * wr, p1 = a1 * wl, q1 = a1 * wr;
    float p2 = a2 * wl, q2 = a2 * wr, p3 = a3 * wl, q3 = a3 * wr;
    for (int off = 32; off > 0; off >>= 1) {
        p0 += __shfl_xor(p0, off); q0 += __shfl_xor(q0, off);
        p1 += __shfl_xor(p1, off); q1 += __shfl_xor(q1, off);
        p2 += __shfl_xor(p2, off); q2 += __shfl_xor(q2, off);
        p3 += __shfl_xor(p3, off); q3 += __shfl_xor(q3, off);
    }
    if (col == 0) {
        al[r + 0] = p0; ar[r + 0] = q0;
        al[r + 1] = p1; ar[r + 1] = q1;
        al[r + 2] = p2; ar[r + 2] = q2;
        al[r + 3] = p3; ar[r + 3] = q3;
    }
}

// ---------------- per-edge coefficient: coef[p] = tanh(al[u]+ar[v]) * norm[p] ----------------
__global__ __launch_bounds__(256) void coef_kernel(const int* __restrict__ csr, const int* __restrict__ rowid,
                                                   const float* __restrict__ norm,
                                                   const float* __restrict__ al, const float* __restrict__ ar,
                                                   float* __restrict__ coef, int tot) {
    int p = blockIdx.x * 256 + threadIdx.x;
    if (p >= tot) return;
    int u = csr[p], v = rowid[p];
    coef[p] = tanhf(al[u] + ar[v]) * norm[p];
}

// ---------------- aggregate: y[v] = relu(sum_in h[u]*coef + eps*x0[v]) ----------------
__global__ __launch_bounds__(256) void aggregate_kernel(const float* __restrict__ h, const float* __restrict__ x0,
                                                        const float* __restrict__ coef,
                                                        const int* __restrict__ offsets, const int* __restrict__ csr,
                                                        float* __restrict__ y, int n) {
    int v = (blockIdx.x * 256 + threadIdx.x) >> 6;
    int lane = threadIdx.x & 63;
    if (v >= n) return;
    int beg = offsets[v], end = offsets[v + 1];
    float acc = 0.f;
    for (int base = beg; base < end; base += 64) {
        int p = base + lane;
        int u = 0; float c = 0.f;
        if (p < end) { u = csr[p]; c = coef[p]; }
        int cnt = min(64, end - base);
#pragma unroll 4
        for (int j = 0; j < cnt; ++j) {
            int uj = __shfl(u, j);
            float cj = __shfl(c, j);
            acc = fmaf(h[(size_t)uj * HID + lane], cj, acc);
        }
    }
    float val = fmaf(EPS_RES, x0[(size_t)v * HID + lane], acc);
    y[(size_t)v * HID + lane] = fmaxf(val, 0.f);
}

// ---------------- batchnorm ----------------
template <int C>
__global__ __launch_bounds__(256) void bn_stats_kernel(const float* __restrict__ y, int rows,
                                                       float* __restrict__ sum, float* __restrict__ sumsq) {
    const int RPB = 256 / C;
    int c = threadIdx.x & (C - 1);
    int r0 = blockIdx.x * RPB + threadIdx.x / C;
    int stride = gridDim.x * RPB;
    float s = 0.f, q = 0.f;
    for (int r = r0; r < rows; r += stride) {
        float v = y[(size_t)r * C + c];
        s += v;
        q = fmaf(v, v, q);
    }
    __shared__ float ls[256], lq[256];
    ls[threadIdx.x] = s; lq[threadIdx.x] = q;
    __syncthreads();
    if (threadIdx.x < C) {
        float ts = 0.f, tq = 0.f;
        for (int j = 0; j < RPB; j++) { ts += ls[c + j * C]; tq += lq[c + j * C]; }
        atomicAdd(&sum[c], ts);
        atomicAdd(&sumsq[c], tq);
    }
}

__global__ void bn_finalize_kernel(const float* __restrict__ sum, const float* __restrict__ sumsq,
                                   const float* __restrict__ g, const float* __restrict__ b,
                                   float rows_inv, int C, float* __restrict__ scale, float* __restrict__ shift) {
    int c = threadIdx.x;
    if (c >= C) return;
    float mean = sum[c] * rows_inv;
    float var = sumsq[c] * rows_inv - mean * mean;
    float sc = g[c] * rsqrtf(var + BN_EPS);
    scale[c] = sc;
    shift[c] = b[c] - mean * sc;
}

// BN apply in-place + attention dots for next layer (wave per row)
__global__ __launch_bounds__(256) void bnapply_attn_kernel(float* __restrict__ y, const float* __restrict__ scale,
                                                           const float* __restrict__ shift,
                                                           const float* __restrict__ attl, const float* __restrict__ attr,
                                                           float* __restrict__ al, float* __restrict__ ar, int n) {
    int v = (blockIdx.x * 256 + threadIdx.x) >> 6;
    int lane = threadIdx.x & 63;
    if (v >= n) return;
    float val = fmaf(y[(size_t)v * HID + lane], scale[lane], shift[lane]);
    y[(size_t)v * HID + lane] = val;
    float pl = val * attl[lane];
    float pr = val * attr[lane];
    for (int off = 32; off > 0; off >>= 1) {
        pl += __shfl_xor(pl, off);
        pr += __shfl_xor(pr, off);
    }
    if (lane == 0) { al[v] = pl; ar[v] = pr; }
}

__global__ __launch_bounds__(256) void bn_apply_kernel(float* __restrict__ y, const float* __restrict__ scale,
                                                       const float* __restrict__ shift, int n4) {
    int i = blockIdx.x * 256 + threadIdx.x;
    if (i >= n4) return;
    float4 v = ((float4*)y)[i];
    int cb = (i * 4) & 63;
    v.x = fmaf(v.x, scale[cb + 0], shift[cb + 0]);
    v.y = fmaf(v.y, scale[cb + 1], shift[cb + 1]);
    v.z = fmaf(v.z, scale[cb + 2], shift[cb + 2]);
    v.w = fmaf(v.w, scale[cb + 3], shift[cb + 3]);
    ((float4*)y)[i] = v;
}

// ---------------- MLP head ----------------
__global__ __launch_bounds__(256) void mlp1_kernel(const float* __restrict__ h, const float* __restrict__ W,
                                                   const float* __restrict__ b, float* __restrict__ z1) {
    __shared__ float Wl[HID * HID];  // 16 KB
    __shared__ float xs[16 * HID];   // 4 KB
    int t = threadIdx.x;
    for (int i = t; i < HID * HID; i += 256) Wl[i] = W[i];
    size_t rowbase = (size_t)blockIdx.x * 16;
    for (int i = t; i < 16 * HID; i += 256) xs[i] = h[rowbase * HID + i];
    __syncthreads();
    int col = t & 63, rg = t >> 6;
    float a0 = 0.f, a1 = 0.f, a2 = 0.f, a3 = 0.f;
    for (int k = 0; k < HID; k++) {
        float wk = Wl[k * HID + col];
        a0 = fmaf(xs[(rg * 4 + 0) * HID + k], wk, a0);
        a1 = fmaf(xs[(rg * 4 + 1) * HID + k], wk, a1);
        a2 = fmaf(xs[(rg * 4 + 2) * HID + k], wk, a2);
        a3 = fmaf(xs[(rg * 4 + 3) * HID + k], wk, a3);
    }
    float bb = b[col];
    size_t r = rowbase + rg * 4;
    z1[(r + 0) * HID + col] = a0 + bb;
    z1[(r + 1) * HID + col] = a1 + bb;
    z1[(r + 2) * HID + col] = a2 + bb;
    z1[(r + 3) * HID + col] = a3 + bb;
}

__global__ __launch_bounds__(256) void mlp2_kernel(const float* __restrict__ z1, const float* __restrict__ scale,
                                                   const float* __restrict__ shift, const float* __restrict__ W,
                                                   const float* __restrict__ b, float* __restrict__ z2) {
    __shared__ float Wl[HID * H2];   // 8 KB
    __shared__ float as[16 * HID];   // 4 KB
    int t = threadIdx.x;
    for (int i = t; i < HID * H2; i += 256) Wl[i] = W[i];
    size_t rowbase = (size_t)blockIdx.x * 16;
    for (int i = t; i < 16 * HID; i += 256) {
        int c = i & 63;
        float v = z1[rowbase * HID + i];
        as[i] = fmaxf(fmaf(v, scale[c], shift[c]), 0.f);
    }
    __syncthreads();
    int col = t & 31, rg = t >> 5;
    float a0 = 0.f, a1 = 0.f;
    for (int k = 0; k < HID; k++) {
        float wk = Wl[k * H2 + col];
        a0 = fmaf(as[(rg * 2 + 0) * HID + k], wk, a0);
        a1 = fmaf(as[(rg * 2 + 1) * HID + k], wk, a1);
    }
    float bb = b[col];
    size_t r = rowbase + rg * 2;
    z2[(r + 0) * H2 + col] = a0 + bb;
    z2[(r + 1) * H2 + col] = a1 + bb;
}

__global__ __launch_bounds__(256) void mlp3_kernel(const float* __restrict__ z2, const float* __restrict__ scale,
                                                   const float* __restrict__ shift, const float* __restrict__ W3,
                                                   const float* __restrict__ b3, float* __restrict__ out, int rows) {
    int i = blockIdx.x * 256 + threadIdx.x;
    if (i >= rows) return;
    float acc = 0.f;
#pragma unroll
    for (int k = 0; k < H2; k++) {
        float v = fmaxf(fmaf(z2[(size_t)i * H2 + k], scale[k], shift[k]), 0.f);
        acc = fmaf(v, W3[k], acc);
    }
    out[i] = acc + b3[0];
}

// ---------------- launch ----------------
extern "C" void kernel_launch(void* const* d_in, const int* in_sizes, int n_in,
                              void* d_out, int out_size, void* d_ws, size_t ws_size,
                              hipStream_t stream) {
    const float* x     = (const float*)d_in[0];
    const int*   ei    = (const int*)d_in[1];
    const int*   src   = ei;
    const int*   dst   = ei + NE;
    const float* W_in  = (const float*)d_in[3];
    const float* b_in  = (const float*)d_in[4];
    const float* att_l = (const float*)d_in[5];
    const float* att_r = (const float*)d_in[6];
    const float* bn_g  = (const float*)d_in[7];
    const float* bn_b  = (const float*)d_in[8];
    const float* W1    = (const float*)d_in[9];
    const float* b1    = (const float*)d_in[10];
    const float* g1    = (const float*)d_in[11];
    const float* be1   = (const float*)d_in[12];
    const float* W2    = (const float*)d_in[13];
    const float* b2    = (const float*)d_in[14];
    const float* g2    = (const float*)d_in[15];
    const float* be2   = (const float*)d_in[16];
    const float* W3    = (const float*)d_in[17];
    const float* b3    = (const float*)d_in[18];
    float* out = (float*)d_out;

    char* p = (char*)d_ws;
    auto carve = [&](size_t bytes) -> void* {
        void* r = (void*)p;
        p += (bytes + 255) & ~(size_t)255;
        return r;
    };
    int*   deg     = (int*)carve((size_t)NND * 4);
    int*   cursor  = (int*)carve((size_t)NND * 4);
    int*   incl    = (int*)carve((size_t)NND * 4);
    int*   offsets = (int*)carve((size_t)(NND + 1) * 4);
    int*   bsum    = (int*)carve(64 * 4);
    int*   boff    = (int*)carve(64 * 4);
    int*   csr     = (int*)carve((size_t)TOT * 4);
    int*   rowid   = (int*)carve((size_t)TOT * 4);
    float* norm    = (float*)carve((size_t)TOT * 4);
    float* coef    = (float*)carve((size_t)TOT * 4);
    float* dinv    = (float*)carve((size_t)NND * 4);
    float* al      = (float*)carve((size_t)NND * 4);
    float* ar      = (float*)carve((size_t)NND * 4);
    float* x0      = (float*)carve((size_t)NND * HID * 4);
    float* hA      = (float*)carve((size_t)NND * HID * 4);
    float* hB      = (float*)carve((size_t)NND * HID * 4);
    float* bn_sum  = (float*)carve(128 * 4);
    float* bn_sq   = bn_sum + 64;
    float* scale   = (float*)carve(64 * 4);
    float* shift   = (float*)carve(64 * 4);
    float* z1      = (float*)carve((size_t)BSZ * HID * 4);
    float* z2      = (float*)carve((size_t)BSZ * H2 * 4);

    const int nblkN = (NND + 255) / 256;
    const int nblkE = (NE + 255) / 256;
    const int nblkT = (TOT + 255) / 256;
    const int nscan = (NND + 1023) / 1024;   // 49

    // --- CSR build ---
    hipMemsetAsync(deg, 0, (size_t)NND * 4, stream);
    deg_count_kernel<<<nblkE, 256, 0, stream>>>(dst, deg, NE);
    scanA_kernel<<<nscan, 1024, 0, stream>>>(deg, incl, bsum, dinv, NND);
    scanB_kernel<<<1, 64, 0, stream>>>(bsum, boff, offsets, nscan, NND);
    scanC_kernel<<<nblkN, 256, 0, stream>>>(incl, deg, boff, dinv, offsets, csr, rowid, norm, cursor, NND);
    scatter_kernel<<<nblkE, 256, 0, stream>>>(src, dst, dinv, cursor, csr, rowid, norm, NE);

    // --- input projection (+ attn dots for layer 0) ---
    gemm_in_kernel<<<NND / 16, 256, 0, stream>>>(x, W_in, b_in, att_l, att_r, x0, al, ar);

    // --- 3 layers: ping-pong hA/hB ---
    const float* h_in = x0;
    float* bufs[2] = {hA, hB};
    for (int l = 0; l < NL; l++) {
        float* y = bufs[l & 1];   // l0: hA (reads x0), l1: hB (reads hA), l2: hA (reads hB)
        coef_kernel<<<nblkT, 256, 0, stream>>>(csr, rowid, norm, al, ar, coef, TOT);
        aggregate_kernel<<<NND / 4, 256, 0, stream>>>(h_in, x0, coef, offsets, csr, y, NND);
        hipMemsetAsync(bn_sum, 0, 128 * sizeof(float), stream);
        bn_stats_kernel<64><<<64, 256, 0, stream>>>(y, NND, bn_sum, bn_sq);
        bn_finalize_kernel<<<1, 64, 0, stream>>>(bn_sum, bn_sq, bn_g + l * HID, bn_b + l * HID,
                                                 1.0f / NND, HID, scale, shift);
        if (l < NL - 1) {
            bnapply_attn_kernel<<<NND / 4, 256, 0, stream>>>(y, scale, shift,
                                                             att_l + (l + 1) * HID, att_r + (l + 1) * HID,
                                                             al, ar, NND);
        } else {
            // only the first BSZ rows feed the MLP head
            bn_apply_kernel<<<(BSZ * HID / 4 + 255) / 256, 256, 0, stream>>>(y, scale, shift, BSZ * HID / 4);
        }
        h_in = y;
    }
    // h_in == hA (final h, BN applied on first BSZ rows)

    // --- MLP head ---
    mlp1_kernel<<<BSZ / 16, 256, 0, stream>>>(h_in, W1, b1, z1);
    hipMemsetAsync(bn_sum, 0, 128 * sizeof(float), stream);
    bn_stats_kernel<64><<<64, 256, 0, stream>>>(z1, BSZ, bn_sum, bn_sq);
    bn_finalize_kernel<<<1, 64, 0, stream>>>(bn_sum, bn_sq, g1, be1, 1.0f / BSZ, HID, scale, shift);

    mlp2_kernel<<<BSZ / 16, 256, 0, stream>>>(z1, scale, shift, W2, b2, z2);
    hipMemsetAsync(bn_sum, 0, 128 * sizeof(float), stream);
    bn_stats_kernel<32><<<64, 256, 0, stream>>>(z2, BSZ, bn_sum, bn_sq);
    bn_finalize_kernel<<<1, 64, 0, stream>>>(bn_sum, bn_sq, g2, be2, 1.0f / BSZ, H2, scale, shift);

    mlp3_kernel<<<(BSZ + 255) / 256, 256, 0, stream>>>(z2, scale, shift, W3, b3, out, BSZ);
}

// Round 4
// 635.789 us; speedup vs baseline: 1.5305x; 1.1536x over previous
//
#include <hip/hip_runtime.h>
#include <hip/hip_bf16.h>
#include <math.h>

#define NND 50000
#define NE  1200000
#define TOT (NE + NND)
#define INCH 128
#define HID 64
#define H2  32
#define NL  3
#define BSZ 10000
#define EPS_RES 0.1f
#define BN_EPS 1e-5f

// ---------------- degree / CSR build ----------------

__global__ __launch_bounds__(256) void deg_count_kernel(const int* __restrict__ dst, int* __restrict__ deg, int ne) {
    int e = blockIdx.x * 256 + threadIdx.x;
    if (e < ne) atomicAdd(&deg[dst[e]], 1);
}

// inclusive scan of 1024-element chunks over (deg+1); also emits dinv
__global__ __launch_bounds__(1024) void scanA_kernel(const int* __restrict__ deg, int* __restrict__ incl,
                                                     int* __restrict__ bsum, float* __restrict__ dinv, int n) {
    __shared__ int ls[1024];
    int tid = threadIdx.x;
    int i = blockIdx.x * 1024 + tid;
    int d = (i < n) ? (deg[i] + 1) : 0;   // +1 = self-loop
    if (i < n) dinv[i] = rsqrtf((float)d);
    ls[tid] = d;
    __syncthreads();
    for (int off = 1; off < 1024; off <<= 1) {
        int t = (tid >= off) ? ls[tid - off] : 0;
        __syncthreads();
        ls[tid] += t;
        __syncthreads();
    }
    if (i < n) incl[i] = ls[tid];
    if (tid == 1023) bsum[blockIdx.x] = ls[1023];
}

// wave-level scan over per-chunk sums (nblk <= 64)
__global__ void scanB_kernel(const int* __restrict__ bsum, int* __restrict__ boff,
                             int* __restrict__ offsets, int nblk, int n) {
    int lane = threadIdx.x;
    int mine = (lane < nblk) ? bsum[lane] : 0;
    int v = mine;
    for (int off = 1; off < 64; off <<= 1) {
        int t = __shfl_up(v, off);
        if (lane >= off) v += t;
    }
    if (lane < nblk) boff[lane] = v - mine;
    if (lane == 63) offsets[n] = v;
}

__global__ __launch_bounds__(256) void scanC_kernel(const int* __restrict__ incl, const int* __restrict__ deg,
                                                    const int* __restrict__ boff,
                                                    int* __restrict__ offsets, int* __restrict__ csr,
                                                    int* __restrict__ cursor, int n) {
    int i = blockIdx.x * 256 + threadIdx.x;
    if (i >= n) return;
    int e = incl[i] - (deg[i] + 1) + boff[i >> 10];  // exclusive offset
    offsets[i] = e;
    csr[e] = i;          // self-loop first
    cursor[i] = e + 1;
}

// scatter ONLY csr (single 4B scattered store per edge)
__global__ __launch_bounds__(256) void scatter_kernel(const int* __restrict__ src, const int* __restrict__ dst,
                                                      int* __restrict__ cursor, int* __restrict__ csr, int ne) {
    int e = blockIdx.x * 256 + threadIdx.x;
    if (e >= ne) return;
    int pos = atomicAdd(&cursor[dst[e]], 1);
    csr[pos] = src[e];
}

// ---------------- input projection: x0 = relu(x @ W_in + b_in), fused attn layer 0, bf16 copy ----------------
__global__ __launch_bounds__(256) void gemm_in_kernel(const float* __restrict__ x, const float* __restrict__ W,
                                                      const float* __restrict__ b,
                                                      const float* __restrict__ attl, const float* __restrict__ attr,
                                                      float* __restrict__ x0, __hip_bfloat16* __restrict__ x0bf,
                                                      float* __restrict__ al, float* __restrict__ ar) {
    __shared__ float Wl[INCH * HID];   // 32 KB
    __shared__ float xs[16 * INCH];    // 8 KB
    int t = threadIdx.x;
    for (int i = t; i < INCH * HID; i += 256) Wl[i] = W[i];
    size_t rowbase = (size_t)blockIdx.x * 16;
    for (int i = t; i < 16 * INCH; i += 256) xs[i] = x[rowbase * INCH + i];
    __syncthreads();
    int col = t & 63, rg = t >> 6;
    float a0 = 0.f, a1 = 0.f, a2 = 0.f, a3 = 0.f;
    for (int k = 0; k < INCH; k++) {
        float wk = Wl[k * HID + col];
        a0 = fmaf(xs[(rg * 4 + 0) * INCH + k], wk, a0);
        a1 = fmaf(xs[(rg * 4 + 1) * INCH + k], wk, a1);
        a2 = fmaf(xs[(rg * 4 + 2) * INCH + k], wk, a2);
        a3 = fmaf(xs[(rg * 4 + 3) * INCH + k], wk, a3);
    }
    float bb = b[col];
    a0 = fmaxf(a0 + bb, 0.f); a1 = fmaxf(a1 + bb, 0.f);
    a2 = fmaxf(a2 + bb, 0.f); a3 = fmaxf(a3 + bb, 0.f);
    size_t r = rowbase + rg * 4;
    x0[(r + 0) * HID + col] = a0;
    x0[(r + 1) * HID + col] = a1;
    x0[(r + 2) * HID + col] = a2;
    x0[(r + 3) * HID + col] = a3;
    x0bf[(r + 0) * HID + col] = __float2bfloat16(a0);
    x0bf[(r + 1) * HID + col] = __float2bfloat16(a1);
    x0bf[(r + 2) * HID + col] = __float2bfloat16(a2);
    x0bf[(r + 3) * HID + col] = __float2bfloat16(a3);
    // fused attention dots for layer 0 (wave rg holds rows r..r+3, lane=channel)
    float wl = attl[col], wr = attr[col];
    float p0 = a0 * wl, q0 = a0 * wr, p1 = a1 * wl, q1 = a1 * wr;
    float p2 = a2 * wl, q2 = a2 * wr, p3 = a3 * wl, q3 = a3 * wr;
    for (int off = 32; off > 0; off >>= 1) {
        p0 += __shfl_xor(p0, off); q0 += __shfl_xor(q0, off);
        p1 += __shfl_xor(p1, off); q1 += __shfl_xor(q1, off);
        p2 += __shfl_xor(p2, off); q2 += __shfl_xor(q2, off);
        p3 += __shfl_xor(p3, off); q3 += __shfl_xor(q3, off);
    }
    if (col == 0) {
        al[r + 0] = p0; ar[r + 0] = q0;
        al[r + 1] = p1; ar[r + 1] = q1;
        al[r + 2] = p2; ar[r + 2] = q2;
        al[r + 3] = p3; ar[r + 3] = q3;
    }
}

// ---------------- aggregate: y[v] = relu(dinv[v]*sum_in h[u]*tanh(al[u]+ar[v])*dinv[u] + eps*x0[v]) ----------------
// wave per node; lane computes one edge's coef (lane-parallel tanh), shuffle-broadcast to all lanes
__global__ __launch_bounds__(256) void aggregate_kernel(const __hip_bfloat16* __restrict__ hbf,
                                                        const float* __restrict__ x0,
                                                        const float* __restrict__ al, const float* __restrict__ ar,
                                                        const float* __restrict__ dinv,
                                                        const int* __restrict__ offsets, const int* __restrict__ csr,
                                                        float* __restrict__ y, int n) {
    int v = (blockIdx.x * 256 + threadIdx.x) >> 6;
    int lane = threadIdx.x & 63;
    if (v >= n) return;
    int beg = offsets[v], end = offsets[v + 1];
    float arv = ar[v];
    float acc = 0.f;
    for (int base = beg; base < end; base += 64) {
        int p = base + lane;
        int u = 0; float c = 0.f;
        if (p < end) {
            u = csr[p];
            c = tanhf(al[u] + arv) * dinv[u];   // dinv[v] factored out of the sum
        }
        int cnt = min(64, end - base);
#pragma unroll 4
        for (int j = 0; j < cnt; ++j) {
            int uj = __shfl(u, j);
            float cj = __shfl(c, j);
            acc = fmaf(__bfloat162float(hbf[(size_t)uj * HID + lane]), cj, acc);
        }
    }
    float val = fmaf(EPS_RES, x0[(size_t)v * HID + lane], acc * dinv[v]);
    y[(size_t)v * HID + lane] = fmaxf(val, 0.f);
}

// ---------------- batchnorm ----------------
template <int C>
__global__ __launch_bounds__(256) void bn_stats_kernel(const float* __restrict__ y, int rows,
                                                       float* __restrict__ sum, float* __restrict__ sumsq) {
    const int RPB = 256 / C;
    int c = threadIdx.x & (C - 1);
    int r0 = blockIdx.x * RPB + threadIdx.x / C;
    int stride = gridDim.x * RPB;
    float s = 0.f, q = 0.f;
    for (int r = r0; r < rows; r += stride) {
        float v = y[(size_t)r * C + c];
        s += v;
        q = fmaf(v, v, q);
    }
    __shared__ float ls[256], lq[256];
    ls[threadIdx.x] = s; lq[threadIdx.x] = q;
    __syncthreads();
    if (threadIdx.x < C) {
        float ts = 0.f, tq = 0.f;
        for (int j = 0; j < RPB; j++) { ts += ls[c + j * C]; tq += lq[c + j * C]; }
        atomicAdd(&sum[c], ts);
        atomicAdd(&sumsq[c], tq);
    }
}

__global__ void bn_finalize_kernel(const float* __restrict__ sum, const float* __restrict__ sumsq,
                                   const float* __restrict__ g, const float* __restrict__ b,
                                   float rows_inv, int C, float* __restrict__ scale, float* __restrict__ shift) {
    int c = threadIdx.x;
    if (c >= C) return;
    float mean = sum[c] * rows_inv;
    float var = sumsq[c] * rows_inv - mean * mean;
    float sc = g[c] * rsqrtf(var + BN_EPS);
    scale[c] = sc;
    shift[c] = b[c] - mean * sc;
}

// BN apply + attention dots for next layer; writes ONLY bf16 h (gather copy)
__global__ __launch_bounds__(256) void bnapply_attn_kernel(const float* __restrict__ y, const float* __restrict__ scale,
                                                           const float* __restrict__ shift,
                                                           const float* __restrict__ attl, const float* __restrict__ attr,
                                                           __hip_bfloat16* __restrict__ hbf,
                                                           float* __restrict__ al, float* __restrict__ ar, int n) {
    int v = (blockIdx.x * 256 + threadIdx.x) >> 6;
    int lane = threadIdx.x & 63;
    if (v >= n) return;
    float val = fmaf(y[(size_t)v * HID + lane], scale[lane], shift[lane]);
    hbf[(size_t)v * HID + lane] = __float2bfloat16(val);
    float pl = val * attl[lane];
    float pr = val * attr[lane];
    for (int off = 32; off > 0; off >>= 1) {
        pl += __shfl_xor(pl, off);
        pr += __shfl_xor(pr, off);
    }
    if (lane == 0) { al[v] = pl; ar[v] = pr; }
}

// final BN apply on first BSZ rows only -> bf16 for MLP
__global__ __launch_bounds__(256) void bn_apply_tail_kernel(const float* __restrict__ y, const float* __restrict__ scale,
                                                            const float* __restrict__ shift,
                                                            __hip_bfloat16* __restrict__ hbf, int total) {
    int i = blockIdx.x * 256 + threadIdx.x;
    if (i >= total) return;
    int c = i & 63;
    hbf[i] = __float2bfloat16(fmaf(y[i], scale[c], shift[c]));
}

// ---------------- MLP head ----------------
__global__ __launch_bounds__(256) void mlp1_kernel(const __hip_bfloat16* __restrict__ h, const float* __restrict__ W,
                                                   const float* __restrict__ b, float* __restrict__ z1) {
    __shared__ float Wl[HID * HID];  // 16 KB
    __shared__ float xs[16 * HID];   // 4 KB
    int t = threadIdx.x;
    for (int i = t; i < HID * HID; i += 256) Wl[i] = W[i];
    size_t rowbase = (size_t)blockIdx.x * 16;
    for (int i = t; i < 16 * HID; i += 256) xs[i] = __bfloat162float(h[rowbase * HID + i]);
    __syncthreads();
    int col = t & 63, rg = t >> 6;
    float a0 = 0.f, a1 = 0.f, a2 = 0.f, a3 = 0.f;
    for (int k = 0; k < HID; k++) {
        float wk = Wl[k * HID + col];
        a0 = fmaf(xs[(rg * 4 + 0) * HID + k], wk, a0);
        a1 = fmaf(xs[(rg * 4 + 1) * HID + k], wk, a1);
        a2 = fmaf(xs[(rg * 4 + 2) * HID + k], wk, a2);
        a3 = fmaf(xs[(rg * 4 + 3) * HID + k], wk, a3);
    }
    float bb = b[col];
    size_t r = rowbase + rg * 4;
    z1[(r + 0) * HID + col] = a0 + bb;
    z1[(r + 1) * HID + col] = a1 + bb;
    z1[(r + 2) * HID + col] = a2 + bb;
    z1[(r + 3) * HID + col] = a3 + bb;
}

__global__ __launch_bounds__(256) void mlp2_kernel(const float* __restrict__ z1, const float* __restrict__ scale,
                                                   const float* __restrict__ shift, const float* __restrict__ W,
                                                   const float* __restrict__ b, float* __restrict__ z2) {
    __shared__ float Wl[HID * H2];   // 8 KB
    __shared__ float as[16 * HID];   // 4 KB
    int t = threadIdx.x;
    for (int i = t; i < HID * H2; i += 256) Wl[i] = W[i];
    size_t rowbase = (size_t)blockIdx.x * 16;
    for (int i = t; i < 16 * HID; i += 256) {
        int c = i & 63;
        float v = z1[rowbase * HID + i];
        as[i] = fmaxf(fmaf(v, scale[c], shift[c]), 0.f);
    }
    __syncthreads();
    int col = t & 31, rg = t >> 5;
    float a0 = 0.f, a1 = 0.f;
    for (int k = 0; k < HID; k++) {
        float wk = Wl[k * H2 + col];
        a0 = fmaf(as[(rg * 2 + 0) * HID + k], wk, a0);
        a1 = fmaf(as[(rg * 2 + 1) * HID + k], wk, a1);
    }
    float bb = b[col];
    size_t r = rowbase + rg * 2;
    z2[(r + 0) * H2 + col] = a0 + bb;
    z2[(r + 1) * H2 + col] = a1 + bb;
}

__global__ __launch_bounds__(256) void mlp3_kernel(const float* __restrict__ z2, const float* __restrict__ scale,
                                                   const float* __restrict__ shift, const float* __restrict__ W3,
                                                   const float* __restrict__ b3, float* __restrict__ out, int rows) {
    int i = blockIdx.x * 256 + threadIdx.x;
    if (i >= rows) return;
    float acc = 0.f;
#pragma unroll
    for (int k = 0; k < H2; k++) {
        float v = fmaxf(fmaf(z2[(size_t)i * H2 + k], scale[k], shift[k]), 0.f);
        acc = fmaf(v, W3[k], acc);
    }
    out[i] = acc + b3[0];
}

// ---------------- launch ----------------
extern "C" void kernel_launch(void* const* d_in, const int* in_sizes, int n_in,
                              void* d_out, int out_size, void* d_ws, size_t ws_size,
                              hipStream_t stream) {
    const float* x     = (const float*)d_in[0];
    const int*   ei    = (const int*)d_in[1];
    const int*   src   = ei;
    const int*   dst   = ei + NE;
    const float* W_in  = (const float*)d_in[3];
    const float* b_in  = (const float*)d_in[4];
    const float* att_l = (const float*)d_in[5];
    const float* att_r = (const float*)d_in[6];
    const float* bn_g  = (const float*)d_in[7];
    const float* bn_b  = (const float*)d_in[8];
    const float* W1    = (const float*)d_in[9];
    const float* b1    = (const float*)d_in[10];
    const float* g1    = (const float*)d_in[11];
    const float* be1   = (const float*)d_in[12];
    const float* W2    = (const float*)d_in[13];
    const float* b2    = (const float*)d_in[14];
    const float* g2    = (const float*)d_in[15];
    const float* be2   = (const float*)d_in[16];
    const float* W3    = (const float*)d_in[17];
    const float* b3    = (const float*)d_in[18];
    float* out = (float*)d_out;

    char* p = (char*)d_ws;
    auto carve = [&](size_t bytes) -> void* {
        void* r = (void*)p;
        p += (bytes + 255) & ~(size_t)255;
        return r;
    };
    int*   deg     = (int*)carve((size_t)NND * 4);
    int*   cursor  = (int*)carve((size_t)NND * 4);
    int*   incl    = (int*)carve((size_t)NND * 4);
    int*   offsets = (int*)carve((size_t)(NND + 1) * 4);
    int*   bsum    = (int*)carve(64 * 4);
    int*   boff    = (int*)carve(64 * 4);
    int*   csr     = (int*)carve((size_t)TOT * 4);
    float* dinv    = (float*)carve((size_t)NND * 4);
    float* al      = (float*)carve((size_t)NND * 4);
    float* ar      = (float*)carve((size_t)NND * 4);
    float* x0      = (float*)carve((size_t)NND * HID * 4);
    __hip_bfloat16* x0bf = (__hip_bfloat16*)carve((size_t)NND * HID * 2);
    __hip_bfloat16* hbfA = (__hip_bfloat16*)carve((size_t)NND * HID * 2);
    __hip_bfloat16* hbfB = (__hip_bfloat16*)carve((size_t)NND * HID * 2);
    float* ybuf    = (float*)carve((size_t)NND * HID * 4);
    float* bn_sum  = (float*)carve(128 * 4);
    float* bn_sq   = bn_sum + 64;
    float* scale   = (float*)carve(64 * 4);
    float* shift   = (float*)carve(64 * 4);
    float* z1      = (float*)carve((size_t)BSZ * HID * 4);
    float* z2      = (float*)carve((size_t)BSZ * H2 * 4);

    const int nblkN = (NND + 255) / 256;
    const int nblkE = (NE + 255) / 256;
    const int nscan = (NND + 1023) / 1024;   // 49

    // --- CSR build ---
    hipMemsetAsync(deg, 0, (size_t)NND * 4, stream);
    deg_count_kernel<<<nblkE, 256, 0, stream>>>(dst, deg, NE);
    scanA_kernel<<<nscan, 1024, 0, stream>>>(deg, incl, bsum, dinv, NND);
    scanB_kernel<<<1, 64, 0, stream>>>(bsum, boff, offsets, nscan, NND);
    scanC_kernel<<<nblkN, 256, 0, stream>>>(incl, deg, boff, offsets, csr, cursor, NND);
    scatter_kernel<<<nblkE, 256, 0, stream>>>(src, dst, cursor, csr, NE);

    // --- input projection (+ attn dots layer 0, bf16 gather copy) ---
    gemm_in_kernel<<<NND / 16, 256, 0, stream>>>(x, W_in, b_in, att_l, att_r, x0, x0bf, al, ar);

    // --- 3 layers ---
    const __hip_bfloat16* h_in = x0bf;
    __hip_bfloat16* hbufs[2] = {hbfA, hbfB};
    for (int l = 0; l < NL; l++) {
        aggregate_kernel<<<NND / 4, 256, 0, stream>>>(h_in, x0, al, ar, dinv, offsets, csr, ybuf, NND);
        hipMemsetAsync(bn_sum, 0, 128 * sizeof(float), stream);
        bn_stats_kernel<64><<<200, 256, 0, stream>>>(ybuf, NND, bn_sum, bn_sq);
        bn_finalize_kernel<<<1, 64, 0, stream>>>(bn_sum, bn_sq, bn_g + l * HID, bn_b + l * HID,
                                                 1.0f / NND, HID, scale, shift);
        if (l < NL - 1) {
            bnapply_attn_kernel<<<NND / 4, 256, 0, stream>>>(ybuf, scale, shift,
                                                             att_l + (l + 1) * HID, att_r + (l + 1) * HID,
                                                             hbufs[l], al, ar, NND);
            h_in = hbufs[l];
        } else {
            bn_apply_tail_kernel<<<(BSZ * HID + 255) / 256, 256, 0, stream>>>(ybuf, scale, shift, hbfA, BSZ * HID);
        }
    }
    // hbfA holds final BN'd h for first BSZ rows

    // --- MLP head ---
    mlp1_kernel<<<BSZ / 16, 256, 0, stream>>>(hbfA, W1, b1, z1);
    hipMemsetAsync(bn_sum, 0, 128 * sizeof(float), stream);
    bn_stats_kernel<64><<<100, 256, 0, stream>>>(z1, BSZ, bn_sum, bn_sq);
    bn_finalize_kernel<<<1, 64, 0, stream>>>(bn_sum, bn_sq, g1, be1, 1.0f / BSZ, HID, scale, shift);

    mlp2_kernel<<<BSZ / 16, 256, 0, stream>>>(z1, scale, shift, W2, b2, z2);
    hipMemsetAsync(bn_sum, 0, 128 * sizeof(float), stream);
    bn_stats_kernel<32><<<100, 256, 0, stream>>>(z2, BSZ, bn_sum, bn_sq);
    bn_finalize_kernel<<<1, 64, 0, stream>>>(bn_sum, bn_sq, g2, be2, 1.0f / BSZ, H2, scale, shift);

    mlp3_kernel<<<(BSZ + 255) / 256, 256, 0, stream>>>(z2, scale, shift, W3, b3, out, BSZ);
}

// Round 6
// 449.182 us; speedup vs baseline: 2.1663x; 1.4154x over previous
//
#include <hip/hip_runtime.h>
#include <hip/hip_bf16.h>
#include <math.h>

#define NND 50000
#define NE  1200000
#define TOT (NE + NND)
#define INCH 128
#define HID 64
#define H2  32
#define NL  3
#define BSZ 10000
#define NB  196          // ceil(NND/256) dst-buckets of 256 nodes
#define CHUNK 2048       // edges per passA block
#define EPS_RES 0.1f
#define BN_EPS 1e-5f

// ---------------- binned CSR build ----------------

// bucket histogram with LDS pre-aggregation
__global__ __launch_bounds__(256) void bhist_kernel(const int* __restrict__ dst, int* __restrict__ bucket_cnt, int ne) {
    __shared__ int arr[256];
    arr[threadIdx.x] = 0;
    __syncthreads();
    int i = blockIdx.x * 256 + threadIdx.x;
    int stride = gridDim.x * 256;
    for (int e = i; e < ne; e += stride) atomicAdd(&arr[dst[e] >> 8], 1);
    __syncthreads();
    int c = arr[threadIdx.x];
    if (c > 0) atomicAdd(&bucket_cnt[threadIdx.x], c);
}

// exclusive scan of bucket counts (single block, Hillis-Steele over 256)
__global__ __launch_bounds__(256) void bscan_kernel(const int* __restrict__ bucket_cnt,
                                                    int* __restrict__ bstart, int* __restrict__ bcur, int nb) {
    __shared__ int ls[256];
    int t = threadIdx.x;
    int v = (t < nb) ? bucket_cnt[t] : 0;
    ls[t] = v;
    __syncthreads();
    for (int off = 1; off < 256; off <<= 1) {
        int tv = (t >= off) ? ls[t - off] : 0;
        __syncthreads();
        ls[t] += tv;
        __syncthreads();
    }
    int excl = ls[t] - v;
    if (t < nb) { bstart[t] = excl; bcur[t] = excl; }
    if (t == 255) bstart[nb] = ls[255];   // = ne
}

// binned scatter: per-block LDS count -> claim contiguous ranges -> dense writes
__global__ __launch_bounds__(256) void passA_kernel(const int* __restrict__ src, const int* __restrict__ dst,
                                                    int* __restrict__ bcur, int2* __restrict__ ebuf, int ne) {
    __shared__ int arr[256];
    int t = threadIdx.x;
    int base = blockIdx.x * CHUNK;
    int lim = min(base + CHUNK, ne);
    arr[t] = 0;
    __syncthreads();
    for (int e = base + t; e < lim; e += 256) atomicAdd(&arr[dst[e] >> 8], 1);
    __syncthreads();
    int cnt_t = arr[t];
    int claimed = 0;
    if (cnt_t > 0) claimed = atomicAdd(&bcur[t], cnt_t);
    __syncthreads();
    arr[t] = claimed;
    __syncthreads();
    for (int e = base + t; e < lim; e += 256) {
        int d = dst[e];
        int pos = atomicAdd(&arr[d >> 8], 1);
        ebuf[pos] = make_int2(src[e], d);
    }
}

// per-bucket degree from dense edge slab (coalesced deg write; no random global atomics)
__global__ __launch_bounds__(256) void bdeg_kernel(const int2* __restrict__ ebuf, const int* __restrict__ bstart,
                                                   int* __restrict__ deg, int n) {
    __shared__ int dcnt[256];
    int b = blockIdx.x, t = threadIdx.x;
    dcnt[t] = 0;
    __syncthreads();
    int beg = bstart[b], end = bstart[b + 1];
    for (int p = beg + t; p < end; p += 256) atomicAdd(&dcnt[ebuf[p].y & 255], 1);
    __syncthreads();
    int node = b * 256 + t;
    if (node < n) deg[node] = dcnt[t];
}

// inclusive scan of 1024-element chunks over (deg+1); also emits dinv
__global__ __launch_bounds__(1024) void scanA_kernel(const int* __restrict__ deg, int* __restrict__ incl,
                                                     int* __restrict__ bsum, float* __restrict__ dinv, int n) {
    __shared__ int ls[1024];
    int tid = threadIdx.x;
    int i = blockIdx.x * 1024 + tid;
    int d = (i < n) ? (deg[i] + 1) : 0;   // +1 = self-loop
    if (i < n) dinv[i] = rsqrtf((float)d);
    ls[tid] = d;
    __syncthreads();
    for (int off = 1; off < 1024; off <<= 1) {
        int t = (tid >= off) ? ls[tid - off] : 0;
        __syncthreads();
        ls[tid] += t;
        __syncthreads();
    }
    if (i < n) incl[i] = ls[tid];
    if (tid == 1023) bsum[blockIdx.x] = ls[1023];
}

__global__ void scanB_kernel(const int* __restrict__ bsum, int* __restrict__ boff,
                             int* __restrict__ offsets, int nblk, int n) {
    int lane = threadIdx.x;
    int mine = (lane < nblk) ? bsum[lane] : 0;
    int v = mine;
    for (int off = 1; off < 64; off <<= 1) {
        int t = __shfl_up(v, off);
        if (lane >= off) v += t;
    }
    if (lane < nblk) boff[lane] = v - mine;
    if (lane == 63) offsets[n] = v;
}

__global__ __launch_bounds__(256) void scanC_kernel(const int* __restrict__ incl, const int* __restrict__ deg,
                                                    const int* __restrict__ boff,
                                                    int* __restrict__ offsets, int* __restrict__ csr, int n) {
    int i = blockIdx.x * 256 + threadIdx.x;
    if (i >= n) return;
    int e = incl[i] - (deg[i] + 1) + boff[i >> 10];  // exclusive offset
    offsets[i] = e;
    csr[e] = i;          // self-loop first
}

// per-bucket placement into final CSR (LDS cursors; dense per-block csr region)
__global__ __launch_bounds__(256) void passB_kernel(const int2* __restrict__ ebuf, const int* __restrict__ bstart,
                                                    const int* __restrict__ offsets, int* __restrict__ csr, int n) {
    __shared__ int cur[256];
    int b = blockIdx.x, t = threadIdx.x;
    int node = b * 256 + t;
    if (node < n) cur[t] = offsets[node] + 1;   // skip self-loop slot
    __syncthreads();
    int beg = bstart[b], end = bstart[b + 1];
    for (int p = beg + t; p < end; p += 256) {
        int2 ed = ebuf[p];
        int pos = atomicAdd(&cur[ed.y & 255], 1);
        csr[pos] = ed.x;
    }
}

// ---------------- input projection: x0 = relu(x @ W_in + b_in), fused attn layer 0, bf16 copy ----------------
__global__ __launch_bounds__(256) void gemm_in_kernel(const float* __restrict__ x, const float* __restrict__ W,
                                                      const float* __restrict__ b,
                                                      const float* __restrict__ attl, const float* __restrict__ attr,
                                                      float* __restrict__ x0, __hip_bfloat16* __restrict__ x0bf,
                                                      float* __restrict__ al, float* __restrict__ ar) {
    __shared__ float Wl[INCH * HID];   // 32 KB
    __shared__ float xs[16 * INCH];    // 8 KB
    int t = threadIdx.x;
    for (int i = t; i < INCH * HID; i += 256) Wl[i] = W[i];
    size_t rowbase = (size_t)blockIdx.x * 16;
    for (int i = t; i < 16 * INCH; i += 256) xs[i] = x[rowbase * INCH + i];
    __syncthreads();
    int col = t & 63, rg = t >> 6;
    float a0 = 0.f, a1 = 0.f, a2 = 0.f, a3 = 0.f;
    for (int k = 0; k < INCH; k++) {
        float wk = Wl[k * HID + col];
        a0 = fmaf(xs[(rg * 4 + 0) * INCH + k], wk, a0);
        a1 = fmaf(xs[(rg * 4 + 1) * INCH + k], wk, a1);
        a2 = fmaf(xs[(rg * 4 + 2) * INCH + k], wk, a2);
        a3 = fmaf(xs[(rg * 4 + 3) * INCH + k], wk, a3);
    }
    float bb = b[col];
    a0 = fmaxf(a0 + bb, 0.f); a1 = fmaxf(a1 + bb, 0.f);
    a2 = fmaxf(a2 + bb, 0.f); a3 = fmaxf(a3 + bb, 0.f);
    size_t r = rowbase + rg * 4;
    x0[(r + 0) * HID + col] = a0;
    x0[(r + 1) * HID + col] = a1;
    x0[(r + 2) * HID + col] = a2;
    x0[(r + 3) * HID + col] = a3;
    x0bf[(r + 0) * HID + col] = __float2bfloat16(a0);
    x0bf[(r + 1) * HID + col] = __float2bfloat16(a1);
    x0bf[(r + 2) * HID + col] = __float2bfloat16(a2);
    x0bf[(r + 3) * HID + col] = __float2bfloat16(a3);
    float wl = attl[col], wr = attr[col];
    float p0 = a0 * wl, q0 = a0 * wr, p1 = a1 * wl, q1 = a1 * wr;
    float p2 = a2 * wl, q2 = a2 * wr, p3 = a3 * wl, q3 = a3 * wr;
    for (int off = 32; off > 0; off >>= 1) {
        p0 += __shfl_xor(p0, off); q0 += __shfl_xor(q0, off);
        p1 += __shfl_xor(p1, off); q1 += __shfl_xor(q1, off);
        p2 += __shfl_xor(p2, off); q2 += __shfl_xor(q2, off);
        p3 += __shfl_xor(p3, off); q3 += __shfl_xor(q3, off);
    }
    if (col == 0) {
        al[r + 0] = p0; ar[r + 0] = q0;
        al[r + 1] = p1; ar[r + 1] = q1;
        al[r + 2] = p2; ar[r + 2] = q2;
        al[r + 3] = p3; ar[r + 3] = q3;
    }
}

// ---------------- aggregate v2: 4 edge-groups x 16 lanes, ushort4 bf16 loads ----------------
// FIX vs R5: wave-uniform iteration count; __shfl executed unconditionally by all 64 lanes
// (clamped source index), FMA/load predicated. Avoids ds_bpermute from exec-masked lanes (UB).
__global__ __launch_bounds__(256) void aggregate_kernel(const __hip_bfloat16* __restrict__ hbf,
                                                        const float* __restrict__ x0,
                                                        const float* __restrict__ al, const float* __restrict__ ar,
                                                        const float* __restrict__ dinv,
                                                        const int* __restrict__ offsets, const int* __restrict__ csr,
                                                        float* __restrict__ y, int n) {
    int v = (blockIdx.x * 256 + threadIdx.x) >> 6;
    int lane = threadIdx.x & 63;
    if (v >= n) return;
    int g = lane >> 4;           // edge subgroup 0..3
    int cl = (lane & 15) << 2;   // channel base (4 channels per lane)
    int beg = offsets[v], end = offsets[v + 1];
    float arv = ar[v];
    float a0 = 0.f, a1 = 0.f, a2 = 0.f, a3 = 0.f;
    for (int base = beg; base < end; base += 64) {
        int p = base + lane;
        int u = 0; float c = 0.f;
        if (p < end) {
            u = csr[p];
            c = tanhf(al[u] + arv) * dinv[u];   // dinv[v] factored out
        }
        int cnt = min(64, end - base);
        int iters = (cnt + 3) >> 2;             // uniform across all lanes
        for (int it = 0; it < iters; ++it) {
            int j = (it << 2) + g;
            int js = (j < cnt) ? j : 0;         // clamp: shfl source always a valid, active lane
            int uj = __shfl(u, js);
            float cj = __shfl(c, js);
            if (j < cnt) {
                ushort4 hv = *(const ushort4*)((const unsigned short*)hbf + (size_t)uj * HID + cl);
                a0 = fmaf(__uint_as_float((unsigned)hv.x << 16), cj, a0);
                a1 = fmaf(__uint_as_float((unsigned)hv.y << 16), cj, a1);
                a2 = fmaf(__uint_as_float((unsigned)hv.z << 16), cj, a2);
                a3 = fmaf(__uint_as_float((unsigned)hv.w << 16), cj, a3);
            }
        }
    }
    a0 += __shfl_xor(a0, 16); a0 += __shfl_xor(a0, 32);
    a1 += __shfl_xor(a1, 16); a1 += __shfl_xor(a1, 32);
    a2 += __shfl_xor(a2, 16); a2 += __shfl_xor(a2, 32);
    a3 += __shfl_xor(a3, 16); a3 += __shfl_xor(a3, 32);
    if (g == 0) {
        float dv = dinv[v];
        float4 x4 = *(const float4*)(x0 + (size_t)v * HID + cl);
        float4 o;
        o.x = fmaxf(fmaf(EPS_RES, x4.x, a0 * dv), 0.f);
        o.y = fmaxf(fmaf(EPS_RES, x4.y, a1 * dv), 0.f);
        o.z = fmaxf(fmaf(EPS_RES, x4.z, a2 * dv), 0.f);
        o.w = fmaxf(fmaf(EPS_RES, x4.w, a3 * dv), 0.f);
        *(float4*)(y + (size_t)v * HID + cl) = o;
    }
}

// ---------------- batchnorm ----------------
template <int C>
__global__ __launch_bounds__(256) void bn_stats_kernel(const float* __restrict__ y, int rows,
                                                       float* __restrict__ sum, float* __restrict__ sumsq) {
    const int RPB = 256 / C;
    int c = threadIdx.x & (C - 1);
    int r0 = blockIdx.x * RPB + threadIdx.x / C;
    int stride = gridDim.x * RPB;
    float s = 0.f, q = 0.f;
    for (int r = r0; r < rows; r += stride) {
        float v = y[(size_t)r * C + c];
        s += v;
        q = fmaf(v, v, q);
    }
    __shared__ float ls[256], lq[256];
    ls[threadIdx.x] = s; lq[threadIdx.x] = q;
    __syncthreads();
    if (threadIdx.x < C) {
        float ts = 0.f, tq = 0.f;
        for (int j = 0; j < RPB; j++) { ts += ls[c + j * C]; tq += lq[c + j * C]; }
        atomicAdd(&sum[c], ts);
        atomicAdd(&sumsq[c], tq);
    }
}

__global__ void bn_finalize_kernel(const float* __restrict__ sum, const float* __restrict__ sumsq,
                                   const float* __restrict__ g, const float* __restrict__ b,
                                   float rows_inv, int C, float* __restrict__ scale, float* __restrict__ shift) {
    int c = threadIdx.x;
    if (c >= C) return;
    float mean = sum[c] * rows_inv;
    float var = sumsq[c] * rows_inv - mean * mean;
    float sc = g[c] * rsqrtf(var + BN_EPS);
    scale[c] = sc;
    shift[c] = b[c] - mean * sc;
}

// BN apply + attention dots for next layer; writes ONLY bf16 h
__global__ __launch_bounds__(256) void bnapply_attn_kernel(const float* __restrict__ y, const float* __restrict__ scale,
                                                           const float* __restrict__ shift,
                                                           const float* __restrict__ attl, const float* __restrict__ attr,
                                                           __hip_bfloat16* __restrict__ hbf,
                                                           float* __restrict__ al, float* __restrict__ ar, int n) {
    int v = (blockIdx.x * 256 + threadIdx.x) >> 6;
    int lane = threadIdx.x & 63;
    if (v >= n) return;
    float val = fmaf(y[(size_t)v * HID + lane], scale[lane], shift[lane]);
    hbf[(size_t)v * HID + lane] = __float2bfloat16(val);
    float pl = val * attl[lane];
    float pr = val * attr[lane];
    for (int off = 32; off > 0; off >>= 1) {
        pl += __shfl_xor(pl, off);
        pr += __shfl_xor(pr, off);
    }
    if (lane == 0) { al[v] = pl; ar[v] = pr; }
}

// final BN apply on first BSZ rows only -> bf16 for MLP
__global__ __launch_bounds__(256) void bn_apply_tail_kernel(const float* __restrict__ y, const float* __restrict__ scale,
                                                            const float* __restrict__ shift,
                                                            __hip_bfloat16* __restrict__ hbf, int total) {
    int i = blockIdx.x * 256 + threadIdx.x;
    if (i >= total) return;
    int c = i & 63;
    hbf[i] = __float2bfloat16(fmaf(y[i], scale[c], shift[c]));
}

// ---------------- MLP head ----------------
__global__ __launch_bounds__(256) void mlp1_kernel(const __hip_bfloat16* __restrict__ h, const float* __restrict__ W,
                                                   const float* __restrict__ b, float* __restrict__ z1) {
    __shared__ float Wl[HID * HID];
    __shared__ float xs[16 * HID];
    int t = threadIdx.x;
    for (int i = t; i < HID * HID; i += 256) Wl[i] = W[i];
    size_t rowbase = (size_t)blockIdx.x * 16;
    for (int i = t; i < 16 * HID; i += 256) xs[i] = __bfloat162float(h[rowbase * HID + i]);
    __syncthreads();
    int col = t & 63, rg = t >> 6;
    float a0 = 0.f, a1 = 0.f, a2 = 0.f, a3 = 0.f;
    for (int k = 0; k < HID; k++) {
        float wk = Wl[k * HID + col];
        a0 = fmaf(xs[(rg * 4 + 0) * HID + k], wk, a0);
        a1 = fmaf(xs[(rg * 4 + 1) * HID + k], wk, a1);
        a2 = fmaf(xs[(rg * 4 + 2) * HID + k], wk, a2);
        a3 = fmaf(xs[(rg * 4 + 3) * HID + k], wk, a3);
    }
    float bb = b[col];
    size_t r = rowbase + rg * 4;
    z1[(r + 0) * HID + col] = a0 + bb;
    z1[(r + 1) * HID + col] = a1 + bb;
    z1[(r + 2) * HID + col] = a2 + bb;
    z1[(r + 3) * HID + col] = a3 + bb;
}

__global__ __launch_bounds__(256) void mlp2_kernel(const float* __restrict__ z1, const float* __restrict__ scale,
                                                   const float* __restrict__ shift, const float* __restrict__ W,
                                                   const float* __restrict__ b, float* __restrict__ z2) {
    __shared__ float Wl[HID * H2];
    __shared__ float as[16 * HID];
    int t = threadIdx.x;
    for (int i = t; i < HID * H2; i += 256) Wl[i] = W[i];
    size_t rowbase = (size_t)blockIdx.x * 16;
    for (int i = t; i < 16 * HID; i += 256) {
        int c = i & 63;
        float v = z1[rowbase * HID + i];
        as[i] = fmaxf(fmaf(v, scale[c], shift[c]), 0.f);
    }
    __syncthreads();
    int col = t & 31, rg = t >> 5;
    float a0 = 0.f, a1 = 0.f;
    for (int k = 0; k < HID; k++) {
        float wk = Wl[k * H2 + col];
        a0 = fmaf(as[(rg * 2 + 0) * HID + k], wk, a0);
        a1 = fmaf(as[(rg * 2 + 1) * HID + k], wk, a1);
    }
    float bb = b[col];
    size_t r = rowbase + rg * 2;
    z2[(r + 0) * H2 + col] = a0 + bb;
    z2[(r + 1) * H2 + col] = a1 + bb;
}

__global__ __launch_bounds__(256) void mlp3_kernel(const float* __restrict__ z2, const float* __restrict__ scale,
                                                   const float* __restrict__ shift, const float* __restrict__ W3,
                                                   const float* __restrict__ b3, float* __restrict__ out, int rows) {
    int i = blockIdx.x * 256 + threadIdx.x;
    if (i >= rows) return;
    float acc = 0.f;
#pragma unroll
    for (int k = 0; k < H2; k++) {
        float v = fmaxf(fmaf(z2[(size_t)i * H2 + k], scale[k], shift[k]), 0.f);
        acc = fmaf(v, W3[k], acc);
    }
    out[i] = acc + b3[0];
}

// ---------------- launch ----------------
extern "C" void kernel_launch(void* const* d_in, const int* in_sizes, int n_in,
                              void* d_out, int out_size, void* d_ws, size_t ws_size,
                              hipStream_t stream) {
    const float* x     = (const float*)d_in[0];
    const int*   ei    = (const int*)d_in[1];
    const int*   src   = ei;
    const int*   dst   = ei + NE;
    const float* W_in  = (const float*)d_in[3];
    const float* b_in  = (const float*)d_in[4];
    const float* att_l = (const float*)d_in[5];
    const float* att_r = (const float*)d_in[6];
    const float* bn_g  = (const float*)d_in[7];
    const float* bn_b  = (const float*)d_in[8];
    const float* W1    = (const float*)d_in[9];
    const float* b1    = (const float*)d_in[10];
    const float* g1    = (const float*)d_in[11];
    const float* be1   = (const float*)d_in[12];
    const float* W2    = (const float*)d_in[13];
    const float* b2    = (const float*)d_in[14];
    const float* g2    = (const float*)d_in[15];
    const float* be2   = (const float*)d_in[16];
    const float* W3    = (const float*)d_in[17];
    const float* b3    = (const float*)d_in[18];
    float* out = (float*)d_out;

    char* p = (char*)d_ws;
    auto carve = [&](size_t bytes) -> void* {
        void* r = (void*)p;
        p += (bytes + 255) & ~(size_t)255;
        return r;
    };
    int*   deg     = (int*)carve((size_t)NND * 4);
    int*   incl    = (int*)carve((size_t)NND * 4);
    int*   offsets = (int*)carve((size_t)(NND + 1) * 4);
    int*   bsum    = (int*)carve(64 * 4);
    int*   boff    = (int*)carve(64 * 4);
    int*   bucket_cnt = (int*)carve(256 * 4);
    int*   bstart  = (int*)carve(256 * 4);
    int*   bcur    = (int*)carve(256 * 4);
    int*   csr     = (int*)carve((size_t)TOT * 4);
    float* dinv    = (float*)carve((size_t)NND * 4);
    float* al      = (float*)carve((size_t)NND * 4);
    float* ar      = (float*)carve((size_t)NND * 4);
    float* x0      = (float*)carve((size_t)NND * HID * 4);
    __hip_bfloat16* x0bf = (__hip_bfloat16*)carve((size_t)NND * HID * 2);
    __hip_bfloat16* hbfA = (__hip_bfloat16*)carve((size_t)NND * HID * 2);
    __hip_bfloat16* hbfB = (__hip_bfloat16*)carve((size_t)NND * HID * 2);
    float* ybuf    = (float*)carve((size_t)NND * HID * 4);
    int2*  ebuf    = (int2*)ybuf;   // alias: ebuf (9.6 MB) lifetime ends before ybuf's begins
    float* bn_sum  = (float*)carve(128 * 4);
    float* bn_sq   = bn_sum + 64;
    float* scale   = (float*)carve(64 * 4);
    float* shift   = (float*)carve(64 * 4);
    float* z1      = (float*)carve((size_t)BSZ * HID * 4);
    float* z2      = (float*)carve((size_t)BSZ * H2 * 4);

    const int nblkN = (NND + 255) / 256;        // 196
    const int nblkA = (NE + CHUNK - 1) / CHUNK; // 586
    const int nscan = (NND + 1023) / 1024;      // 49

    // --- binned CSR build ---
    hipMemsetAsync(bucket_cnt, 0, 256 * 4, stream);
    bhist_kernel<<<512, 256, 0, stream>>>(dst, bucket_cnt, NE);
    bscan_kernel<<<1, 256, 0, stream>>>(bucket_cnt, bstart, bcur, NB);
    passA_kernel<<<nblkA, 256, 0, stream>>>(src, dst, bcur, ebuf, NE);
    bdeg_kernel<<<NB, 256, 0, stream>>>(ebuf, bstart, deg, NND);
    scanA_kernel<<<nscan, 1024, 0, stream>>>(deg, incl, bsum, dinv, NND);
    scanB_kernel<<<1, 64, 0, stream>>>(bsum, boff, offsets, nscan, NND);
    scanC_kernel<<<nblkN, 256, 0, stream>>>(incl, deg, boff, offsets, csr, NND);
    passB_kernel<<<NB, 256, 0, stream>>>(ebuf, bstart, offsets, csr, NND);

    // --- input projection (+ attn dots layer 0, bf16 gather copy) ---
    gemm_in_kernel<<<NND / 16, 256, 0, stream>>>(x, W_in, b_in, att_l, att_r, x0, x0bf, al, ar);

    // --- 3 layers ---
    const __hip_bfloat16* h_in = x0bf;
    __hip_bfloat16* hbufs[2] = {hbfA, hbfB};
    for (int l = 0; l < NL; l++) {
        aggregate_kernel<<<NND / 4, 256, 0, stream>>>(h_in, x0, al, ar, dinv, offsets, csr, ybuf, NND);
        hipMemsetAsync(bn_sum, 0, 128 * sizeof(float), stream);
        bn_stats_kernel<64><<<200, 256, 0, stream>>>(ybuf, NND, bn_sum, bn_sq);
        bn_finalize_kernel<<<1, 64, 0, stream>>>(bn_sum, bn_sq, bn_g + l * HID, bn_b + l * HID,
                                                 1.0f / NND, HID, scale, shift);
        if (l < NL - 1) {
            bnapply_attn_kernel<<<NND / 4, 256, 0, stream>>>(ybuf, scale, shift,
                                                             att_l + (l + 1) * HID, att_r + (l + 1) * HID,
                                                             hbufs[l], al, ar, NND);
            h_in = hbufs[l];
        } else {
            bn_apply_tail_kernel<<<(BSZ * HID + 255) / 256, 256, 0, stream>>>(ybuf, scale, shift, hbfA, BSZ * HID);
        }
    }

    // --- MLP head ---
    mlp1_kernel<<<BSZ / 16, 256, 0, stream>>>(hbfA, W1, b1, z1);
    hipMemsetAsync(bn_sum, 0, 128 * sizeof(float), stream);
    bn_stats_kernel<64><<<100, 256, 0, stream>>>(z1, BSZ, bn_sum, bn_sq);
    bn_finalize_kernel<<<1, 64, 0, stream>>>(bn_sum, bn_sq, g1, be1, 1.0f / BSZ, HID, scale, shift);

    mlp2_kernel<<<BSZ / 16, 256, 0, stream>>>(z1, scale, shift, W2, b2, z2);
    hipMemsetAsync(bn_sum, 0, 128 * sizeof(float), stream);
    bn_stats_kernel<32><<<100, 256, 0, stream>>>(z2, BSZ, bn_sum, bn_sq);
    bn_finalize_kernel<<<1, 64, 0, stream>>>(bn_sum, bn_sq, g2, be2, 1.0f / BSZ, H2, scale, shift);

    mlp3_kernel<<<(BSZ + 255) / 256, 256, 0, stream>>>(z2, scale, shift, W3, b3, out, BSZ);
}